// Round 5
// baseline (751.077 us; speedup 1.0000x reference)
//
#include <hip/hip_runtime.h>
#include <stdint.h>

#define NF 51
#define UNITS 128
#define G3 384
#define OUT_C 102
#define NW 13158            // UNITS*OUT_C + OUT_C
#define GAMMA 28
#define BATCH 8192
#define SEQ_T 64
#define TSTEPS 50           // 64 - LAG(14)
#define NDEC 27
#define BR 32               // batch rows per block
#define THREADS 1024        // 16 waves
#define CCONST 0.5413248546129181f
#define WF_USHORTS 147456   // 24 nb * 6 ks * 2 split * 512
#define WDF_USHORTS 802816  // 28 g * 7 nt * 4 ks * 2 split * 512
#define WDF_FRAG_THREADS 401408  // 28*7*4*64*8
#define HB_ELEMS 2856       // 28 * 102
#define WXL_USHORTS 49152   // 24 nb * 2 ks * 2 split * 512 (96 KB in LDS)

typedef __attribute__((ext_vector_type(8))) short bf16x8;
typedef __attribute__((ext_vector_type(4))) float f32x4;
typedef unsigned short ushort_t;

#define MFMA16(a, b, c) __builtin_amdgcn_mfma_f32_16x16x32_bf16((a), (b), (c), 0, 0, 0)

// ---------- JAX threefry2x32 (20 rounds), host+device ----------
__host__ __device__ __forceinline__ void tf2x32(uint32_t k0, uint32_t k1,
    uint32_t x0, uint32_t x1, uint32_t& o0, uint32_t& o1)
{
  uint32_t ks2 = k0 ^ k1 ^ 0x1BD11BDAu;
  x0 += k0; x1 += k1;
#define TF_R(r) { x0 += x1; x1 = (x1 << (r)) | (x1 >> (32 - (r))); x1 ^= x0; }
  TF_R(13) TF_R(15) TF_R(26) TF_R(6)  x0 += k1;  x1 += ks2 + 1u;
  TF_R(17) TF_R(29) TF_R(16) TF_R(24) x0 += ks2; x1 += k0 + 2u;
  TF_R(13) TF_R(15) TF_R(26) TF_R(6)  x0 += k0;  x1 += k1 + 3u;
  TF_R(17) TF_R(29) TF_R(16) TF_R(24) x0 += k1;  x1 += ks2 + 4u;
  TF_R(13) TF_R(15) TF_R(26) TF_R(6)  x0 += ks2; x1 += k0 + 5u;
#undef TF_R
  o0 = x0; o1 = x1;
}

// XLA ErfInv32 (Giles)
__device__ __forceinline__ float erfinv_f(float x) {
  float w = -log1pf(-x * x);
  float p;
  if (w < 5.0f) {
    w -= 2.5f;
    p = 2.81022636e-08f;
    p = fmaf(p, w, 3.43273939e-07f);
    p = fmaf(p, w, -3.5233877e-06f);
    p = fmaf(p, w, -4.39150654e-06f);
    p = fmaf(p, w, 0.00021858087f);
    p = fmaf(p, w, -0.00125372503f);
    p = fmaf(p, w, -0.00417768164f);
    p = fmaf(p, w, 0.246640727f);
    p = fmaf(p, w, 1.50140941f);
  } else {
    w = sqrtf(w) - 3.0f;
    p = -0.000200214257f;
    p = fmaf(p, w, 0.000100950558f);
    p = fmaf(p, w, 0.00134934322f);
    p = fmaf(p, w, -0.00367342844f);
    p = fmaf(p, w, 0.00573950773f);
    p = fmaf(p, w, -0.0076224613f);
    p = fmaf(p, w, 0.00943887047f);
    p = fmaf(p, w, 1.00167406f);
    p = fmaf(p, w, 2.83297682f);
  }
  return p * x;
}

__device__ __forceinline__ float jax_normal(uint32_t k0, uint32_t k1, uint32_t i)
{
  uint32_t y0, y1;
  tf2x32(k0, k1, 0u, i, y0, y1);
  uint32_t bits = y0 ^ y1;
  uint32_t fb = (bits >> 9) | 0x3f800000u;
  float f = __uint_as_float(fb) - 1.0f;       // [0,1)
  const float lo = -0.99999994f;
  const float d  = 1.99999994f;
  float u = __fadd_rn(__fmul_rn(f, d), lo);   // XLA uses mul+add (no fma)
  u = fmaxf(lo, u);
  return 1.41421354f * erfinv_f(u);
}

__device__ __forceinline__ float softplus_f(float x) {
  return fmaxf(x, 0.0f) + log1pf(expf(-fabsf(x)));
}
// fast gate nonlinearities: v_exp + v_rcp, ~1e-6 abs error (gates only)
__device__ __forceinline__ float rcp_f(float x) { return __builtin_amdgcn_rcpf(x); }
__device__ __forceinline__ float sigmoid_fast(float x) {
  return rcp_f(1.0f + __expf(-x));
}
__device__ __forceinline__ float tanh_fast(float x) {
  return 1.0f - 2.0f * rcp_f(1.0f + __expf(2.0f * x));  // saturates correctly
}

// f32 <-> bf16 bits (RNE)
__device__ __forceinline__ ushort_t f2bf(float f) {
  uint32_t u = __float_as_uint(f);
  uint32_t r = (u + 0x7fffu + ((u >> 16) & 1u)) >> 16;
  return (ushort_t)r;
}
__device__ __forceinline__ float bf2f(ushort_t h) {
  return __uint_as_float(((uint32_t)h) << 16);
}

// ---------- prep kernel 1: GRU weights -> MFMA B-fragments (split-bf16) ----
// Layout: WF[nb(24)][ks(6)][split(2)][lane(64)][elem(8)] ushorts.
// nb = 16-col tile of 384 gate cols. ks 0..3 = Wh rows, ks 4..5 = Wx (padded).
__global__ void build_wf_kernel(const float* __restrict__ Wh,   // (128,384)
                                const float* __restrict__ Wx,   // (51,384)
                                ushort_t* __restrict__ wf)
{
  int t = blockIdx.x * 256 + threadIdx.x;
  if (t >= WF_USHORTS) return;
  int e    = t & 7;
  int lane = (t >> 3) & 63;
  int sp   = (t >> 9) & 1;
  int q    = t >> 10;          // nb*6 + ks
  int ks   = q % 6;
  int nb   = q / 6;
  int kl   = 8 * (lane >> 4) + e;
  int col  = 16 * nb + (lane & 15);
  float w;
  if (ks < 4) {
    w = Wh[(32 * ks + kl) * G3 + col];
  } else {
    int row = 32 * (ks - 4) + kl;
    w = (row < NF) ? Wx[row * G3 + col] : 0.0f;
  }
  ushort_t hi = f2bf(w);
  wf[t] = (sp == 0) ? hi : f2bf(w - bf2f(hi));
}

// ---------- prep kernel 2: sample decoder weights DIRECTLY into fragments ----
// WDF[g(28)*7+nt][ks(4)][split(2)][lane(64)][elem(8)]; cols>=102 zero-padded.
// Plus hbias[g][col] f32.
__global__ void build_wdf_kernel(const float* __restrict__ post_loc,
                                 const float* __restrict__ post_rho,
                                 ushort_t* __restrict__ wdf,
                                 float* __restrict__ hbias,
                                 uint32_t kw0, uint32_t kw1)
{
  int t = blockIdx.x * 256 + threadIdx.x;
  if (t < WDF_FRAG_THREADS) {
    int e    = t & 7;
    int lane = (t >> 3) & 63;
    int ks   = (t >> 9) & 3;
    int q    = t >> 11;          // g*7 + nt
    int nt   = q % 7;
    int g    = q / 7;
    int k    = 32 * ks + 8 * (lane >> 4) + e;
    int col  = 16 * nt + (lane & 15);
    float w = 0.0f;
    if (col < OUT_C) {
      int widx = k * OUT_C + col;
      float eps = jax_normal(kw0, kw1, (uint32_t)(g * NW + widx));
      float sc = 1e-5f + 0.02f * softplus_f(CCONST + post_rho[widx]);
      w = fmaf(sc, eps, post_loc[widx]);
    }
    ushort_t hi = f2bf(w);
    size_t base = (size_t)(q * 4 + ks) * 1024 + lane * 8 + e;
    wdf[base]       = hi;
    wdf[base + 512] = f2bf(w - bf2f(hi));
  } else if (t < WDF_FRAG_THREADS + HB_ELEMS) {
    int u = t - WDF_FRAG_THREADS;
    int col = u % OUT_C, g = u / OUT_C;
    int widx = UNITS * OUT_C + col;
    float eps = jax_normal(kw0, kw1, (uint32_t)(g * NW + widx));
    float sc = 1e-5f + 0.02f * softplus_f(CCONST + post_rho[widx]);
    hbias[u] = fmaf(sc, eps, post_loc[widx]);
  }
}

// ---------- main kernel ----------
// Waves 0..7 own the z/r/h tile triple for n-group g3 and BOTH m-tiles;
// gates fully in-register (hreg[8]). This round:
//  * Wx fragments (96 KB) live in LDS, loaded once -> L2 stream/step 288->192KB
//  * streamed Wh fragments use a 2-bank register pipeline (B0/B1, 12 frags in
//    flight) so L2 latency hides under the previous ks's 18 mfma.
__global__ __launch_bounds__(THREADS, 4)
__attribute__((amdgpu_waves_per_eu(4, 4)))
void irnn_main(
    const float* __restrict__ x,      // (8192, 64, 51)
    const float* __restrict__ gbias,  // (2, 384)
    const ushort_t* __restrict__ WF,  // GRU fragment weights
    const ushort_t* __restrict__ WDF, // head fragment weights
    const float* __restrict__ HB,     // head bias (28,102)
    float* __restrict__ out,          // (8192, 28, 102)
    uint32_t ks0, uint32_t ks1)
{
  __shared__ __align__(16) ushort_t h_hi[BR][136];     // bf16 hi, pad 128->136
  __shared__ __align__(16) ushort_t h_lo[BR][136];
  __shared__ __align__(16) ushort_t s_hi[2][BR][72];   // double-buffered
  __shared__ __align__(16) ushort_t s_lo[2][BR][72];   // (K-pad 52..63 zero)
  __shared__ float t_lds[BR][OUT_C];
  __shared__ __align__(16) ushort_t wx_lds[WXL_USHORTS]; // Wx frags, 96 KB

  const int tid  = threadIdx.x;
  const int b0   = blockIdx.x * BR;
  const int lane = tid & 63;
  const int wv   = tid >> 6;          // 0..15
  const int kg   = lane >> 4;         // k-group 0..3
  const int fr   = lane & 15;         // frag row (A) / col (B,D)
  const int g3   = wv & 7;            // n-tile group (GRU waves: wv<8)
  const int c    = 16 * g3 + fr;      // unit column owned by this thread

  // gate biases for unit c
  const float bz  = gbias[c]           + gbias[G3 + c];
  const float brg = gbias[UNITS + c]   + gbias[G3 + UNITS + c];
  const float bxh = gbias[2*UNITS + c];
  const float brh = gbias[G3 + 2*UNITS + c];

  float hreg[8] = {0.f,0.f,0.f,0.f,0.f,0.f,0.f,0.f}; // h at (16m+4kg+j, c)
  f32x4 cz[2], cr[2], crh[2], cxh[2];                // GRU acc chains

  for (int i = tid; i < BR * 136; i += THREADS) { (&h_hi[0][0])[i] = 0; (&h_lo[0][0])[i] = 0; }
  for (int i = tid; i < 2 * BR * 72; i += THREADS) { (&s_hi[0][0][0])[i] = 0; (&s_lo[0][0][0])[i] = 0; }
  // Wx fragments -> LDS (once). wx_lds chunk = nb*4 + (ks-4)*2 + sp, 512 us each.
  for (int i = tid; i < WXL_USHORTS / 8; i += THREADS) {
    int e = i * 8;
    int chunk  = e >> 9;
    int within = e & 511;
    int nb = chunk >> 2;
    int r  = chunk & 3;
    const ushort_t* src = WF + ((size_t)(nb * 6 + 4 + (r >> 1)) * 2 + (r & 1)) * 512 + within;
    *(uint4*)&wx_lds[e] = *(const uint4*)src;
  }
  __syncthreads();

  const ushort_t* wfz = WF + (size_t)g3        * 6144 + (size_t)lane * 8;
  const ushort_t* wfr = WF + (size_t)(8 + g3)  * 6144 + (size_t)lane * 8;
  const ushort_t* wfh = WF + (size_t)(16 + g3) * 6144 + (size_t)lane * 8;
  const ushort_t* wxz = wx_lds + g3        * 2048 + lane * 8;
  const ushort_t* wxr = wx_lds + (8 + g3)  * 2048 + lane * 8;
  const ushort_t* wxh = wx_lds + (16 + g3) * 2048 + lane * 8;

// load one ks-worth of B-fragments (z hi/lo, r hi/lo, h hi/lo) into bank B
#define LDB(B, KS, PZ, PR, PH)                           \
  B[0] = *(const bf16x8*)((PZ) + (2*(KS)+0) * 512);      \
  B[1] = *(const bf16x8*)((PZ) + (2*(KS)+1) * 512);      \
  B[2] = *(const bf16x8*)((PR) + (2*(KS)+0) * 512);      \
  B[3] = *(const bf16x8*)((PR) + (2*(KS)+1) * 512);      \
  B[4] = *(const bf16x8*)((PH) + (2*(KS)+0) * 512);      \
  B[5] = *(const bf16x8*)((PH) + (2*(KS)+1) * 512);

  // ---- one ks step: 18 mfma, 8 interleaved chains (per-chain order fixed) ----
  auto do_ks = [&](const bf16x8* B,
                   const ushort_t* Ah0, const ushort_t* Al0,
                   const ushort_t* Ah1, const ushort_t* Al1, f32x4* chh) {
    bf16x8 ah[2], al[2];
    ah[0] = *(const bf16x8*)Ah0;  al[0] = *(const bf16x8*)Al0;
    ah[1] = *(const bf16x8*)Ah1;  al[1] = *(const bf16x8*)Al1;
    #pragma unroll
    for (int m = 0; m < 2; ++m) cz[m]  = MFMA16(ah[m], B[0], cz[m]);
    #pragma unroll
    for (int m = 0; m < 2; ++m) cr[m]  = MFMA16(ah[m], B[2], cr[m]);
    #pragma unroll
    for (int m = 0; m < 2; ++m) chh[m] = MFMA16(ah[m], B[4], chh[m]);
    #pragma unroll
    for (int m = 0; m < 2; ++m) cz[m]  = MFMA16(ah[m], B[1], cz[m]);
    #pragma unroll
    for (int m = 0; m < 2; ++m) cr[m]  = MFMA16(ah[m], B[3], cr[m]);
    #pragma unroll
    for (int m = 0; m < 2; ++m) chh[m] = MFMA16(ah[m], B[5], chh[m]);
    #pragma unroll
    for (int m = 0; m < 2; ++m) cz[m]  = MFMA16(al[m], B[0], cz[m]);
    #pragma unroll
    for (int m = 0; m < 2; ++m) cr[m]  = MFMA16(al[m], B[2], cr[m]);
    #pragma unroll
    for (int m = 0; m < 2; ++m) chh[m] = MFMA16(al[m], B[4], chh[m]);
  };

  // ---- GRU mfma: 2-bank pipelined Wh stream + Wx from LDS ----
  auto gru_mfma = [&](int buf) {
    #pragma unroll
    for (int m = 0; m < 2; ++m) {
      cz[m]  = (f32x4){0.f,0.f,0.f,0.f};
      cr[m]  = (f32x4){0.f,0.f,0.f,0.f};
      crh[m] = (f32x4){0.f,0.f,0.f,0.f};
      cxh[m] = (f32x4){0.f,0.f,0.f,0.f};
    }
    bf16x8 B0[6], B1[6];
    LDB(B0, 0, wfz, wfr, wfh);
    LDB(B1, 1, wfz, wfr, wfh);
    do_ks(B0, &h_hi[fr][8*kg],      &h_lo[fr][8*kg],
              &h_hi[16+fr][8*kg],   &h_lo[16+fr][8*kg],   crh);
    LDB(B0, 2, wfz, wfr, wfh);
    do_ks(B1, &h_hi[fr][32+8*kg],   &h_lo[fr][32+8*kg],
              &h_hi[16+fr][32+8*kg],&h_lo[16+fr][32+8*kg],crh);
    LDB(B1, 3, wfz, wfr, wfh);
    do_ks(B0, &h_hi[fr][64+8*kg],   &h_lo[fr][64+8*kg],
              &h_hi[16+fr][64+8*kg],&h_lo[16+fr][64+8*kg],crh);
    do_ks(B1, &h_hi[fr][96+8*kg],   &h_lo[fr][96+8*kg],
              &h_hi[16+fr][96+8*kg],&h_lo[16+fr][96+8*kg],crh);
    // input part: B from LDS (wx ks index 0 -> GRU ks4, 1 -> ks5)
    LDB(B0, 0, wxz, wxr, wxh);
    do_ks(B0, &s_hi[buf][fr][8*kg],       &s_lo[buf][fr][8*kg],
              &s_hi[buf][16+fr][8*kg],    &s_lo[buf][16+fr][8*kg],    cxh);
    LDB(B1, 1, wxz, wxr, wxh);
    do_ks(B1, &s_hi[buf][fr][32+8*kg],    &s_lo[buf][fr][32+8*kg],
              &s_hi[buf][16+fr][32+8*kg], &s_lo[buf][16+fr][32+8*kg], cxh);
  };

  // ---- gate elementwise + h update + bf16 split (in-register) ----
  auto combine = [&]() {
    #pragma unroll
    for (int m = 0; m < 2; ++m) {
      const int orow = 16*m + 4*kg;
      #pragma unroll
      for (int j = 0; j < 4; ++j) {
        float az = cz[m][j]  + bz;
        float ar = cr[m][j]  + brg;
        float rh = crh[m][j] + brh;
        float xh = cxh[m][j] + bxh;
        float z  = sigmoid_fast(az);
        float rr = sigmoid_fast(ar);
        float hh = tanh_fast(fmaf(rr, rh, xh));
        float h  = z * hreg[4*m + j] + (1.0f - z) * hh;
        hreg[4*m + j] = h;
        ushort_t hi = f2bf(h);
        h_hi[orow + j][c] = hi;
        h_lo[orow + j][c] = f2bf(h - bf2f(hi));
      }
    }
  };

  // ---- head: t = h @ K_g + b_g on MFMA (waves 0..13: 2m x 7n tiles) ----
  auto head = [&](int g) {
    if (wv < 14) {
      const int nt = wv % 7, mt = wv / 7;
      const ushort_t* WB = WDF + (size_t)(g * 7 + nt) * 4096 + (size_t)lane * 8;
      f32x4 acc = {0.f,0.f,0.f,0.f};
      #pragma unroll 2
      for (int ks = 0; ks < 4; ++ks) {
        const int off = 32*ks + 8*kg;
        bf16x8 ah = *(const bf16x8*)&h_hi[16*mt + fr][off];
        bf16x8 al = *(const bf16x8*)&h_lo[16*mt + fr][off];
        bf16x8 bh = *(const bf16x8*)(WB + (2*ks + 0) * 512);
        bf16x8 bl = *(const bf16x8*)(WB + (2*ks + 1) * 512);
        acc = MFMA16(ah, bh, acc);
        acc = MFMA16(ah, bl, acc);
        acc = MFMA16(al, bh, acc);
      }
      const int col = 16*nt + fr;
      if (col < OUT_C) {
        float kb = HB[g * OUT_C + col];
        const int r0 = 16*mt + 4*kg;
        #pragma unroll
        for (int j = 0; j < 4; ++j) {
          float tv = acc[j] + kb;
          t_lds[r0 + j][col] = tv;
          float ov = (col < NF) ? tv
                               : (1e-5f + 0.05f * softplus_f(CCONST + tv));
          out[(size_t)(b0 + r0 + j) * (GAMMA * OUT_C) + g * OUT_C + col] = ov;
        }
      }
    }
  };

  // ---- decoder input: s = loc + scale * eps_s[j] -> s buffer 0 ----
  auto sphase = [&](int j) {
    for (int idx = tid; idx < BR * NF; idx += THREADS) {
      int r = idx / NF, f = idx - r * NF;
      float loc = t_lds[r][f];
      float sc = 1e-5f + 0.05f * softplus_f(CCONST + t_lds[r][NF + f]);
      uint32_t gi = (uint32_t)((j * BATCH + b0 + r) * NF + f);
      float es = jax_normal(ks0, ks1, gi);
      float s = fmaf(sc, es, loc);
      ushort_t hi = f2bf(s);
      s_hi[0][r][f] = hi;
      s_lo[0][r][f] = f2bf(s - bf2f(hi));
    }
  };

  // ---- encoder: 50 steps; GRU waves compute while loader waves prefetch ----
  for (int idx = tid; idx < BR * NF; idx += THREADS) {   // preload x(0) -> s[0]
    int r = idx / NF, f = idx - r * NF;
    float v = x[(size_t)(b0 + r) * (SEQ_T * NF) + f];
    ushort_t hi = f2bf(v);
    s_hi[0][r][f] = hi;
    s_lo[0][r][f] = f2bf(v - bf2f(hi));
  }
  __syncthreads();
  for (int t = 0; t < TSTEPS; ++t) {
    if (wv < 8) {
      gru_mfma(t & 1);
    } else if (t + 1 < TSTEPS) {
      const int nb = (t + 1) & 1;
      for (int idx = tid - 512; idx < BR * NF; idx += 512) {
        int r = idx / NF, f = idx - r * NF;
        float v = x[(size_t)(b0 + r) * (SEQ_T * NF) + (t + 1) * NF + f];
        ushort_t hi = f2bf(v);
        s_hi[nb][r][f] = hi;
        s_lo[nb][r][f] = f2bf(v - bf2f(hi));
      }
    }
    __syncthreads();          // mfma h/s reads done; next-s written
    if (wv < 8) combine();
    __syncthreads();          // h visible
  }
  head(0);
  __syncthreads();            // t_lds visible

  // ---- decoder: 27 steps ----
  for (int j = 0; j < NDEC; ++j) {
    sphase(j);                // writes s buffer 0
    __syncthreads();
    if (wv < 8) gru_mfma(0);
    __syncthreads();          // mfma reads done
    if (wv < 8) combine();
    __syncthreads();          // h visible
    head(j + 1);
    __syncthreads();          // t_lds visible
  }
}

extern "C" void kernel_launch(void* const* d_in, const int* in_sizes, int n_in,
                              void* d_out, int out_size, void* d_ws, size_t ws_size,
                              hipStream_t stream)
{
  const float* x    = (const float*)d_in[0];
  const float* gk   = (const float*)d_in[1];   // (51, 384)
  const float* grk  = (const float*)d_in[2];   // (128, 384)
  const float* gb   = (const float*)d_in[3];
  const float* ploc = (const float*)d_in[4];
  const float* prho = (const float*)d_in[5];

  ushort_t* wf  = (ushort_t*)d_ws;                 // 294912 B
  ushort_t* wdf = wf + WF_USHORTS;                 // 1605632 B
  float*    hb  = (float*)(wdf + WDF_USHORTS);     // 11424 B

  uint32_t kw0, kw1, ksd0, ksd1;
  tf2x32(0u, 42u, 0u, 0u, kw0, kw1);
  tf2x32(0u, 42u, 0u, 1u, ksd0, ksd1);

  build_wf_kernel<<<(WF_USHORTS + 255) / 256, 256, 0, stream>>>(grk, gk, wf);
  build_wdf_kernel<<<(WDF_FRAG_THREADS + HB_ELEMS + 255) / 256, 256, 0, stream>>>(
      ploc, prho, wdf, hb, kw0, kw1);
  irnn_main<<<BATCH / BR, THREADS, 0, stream>>>(x, gb, wf, wdf, hb,
                                                (float*)d_out, ksd0, ksd1);
}